// Round 11
// baseline (135.604 us; speedup 1.0000x reference)
//
#include <hip/hip_runtime.h>
#include <hip/hip_bf16.h>

#define NB 16
#define NC 128
#define NN 2048
#define NF 64
#define NEG_SLOPE 0.33f
#define EXP_K 1.4426950408889634f   // log2(e)

typedef float    f32x2 __attribute__((ext_vector_type(2)));
typedef float    f32x4 __attribute__((ext_vector_type(4)));
typedef _Float16 f16x2 __attribute__((ext_vector_type(2)));
typedef _Float16 f16x4 __attribute__((ext_vector_type(4)));
typedef _Float16 f16x8 __attribute__((ext_vector_type(8)));

__device__ __forceinline__ float lrelu(float x) {
    return fmaxf(x, x * NEG_SLOPE);
}

// Kernel 1: Wh = h^T @ W in fp32 (VALU, LDS-tiled); emit WhT f16 [b][f][n],
// s1 = Wh@a1, s2 = Wh@a2 in fp32.  (unchanged)
__global__ __launch_bounds__(256) void k_precompute(
    const float* __restrict__ h, const float* __restrict__ W,
    const float* __restrict__ a, _Float16* __restrict__ wht,
    float* __restrict__ s1g, float* __restrict__ s2g)
{
    __shared__ float Wl[64 * 64];
    __shared__ float ht[64 * 129];

    const int t = threadIdx.x;
    const int b = blockIdx.x >> 5;
    const int n0 = (blockIdx.x & 31) << 6;
    const int lane = t & 63, cg = t >> 6;

    #pragma unroll 8
    for (int k = 0; k < 32; ++k) {
        const int c = cg * 32 + k;
        ht[lane * 129 + c] = h[(size_t)(b * NC + c) * NN + n0 + lane];
    }

    const int fg = t & 15, ns = t >> 4;
    f32x4 acc[4] = {};
    for (int half = 0; half < 2; ++half) {
        if (half) __syncthreads();
        #pragma unroll
        for (int k = 0; k < 4; ++k) {
            const int idx = k * 1024 + t * 4;
            *(f32x4*)&Wl[idx] = *(const f32x4*)&W[half * 4096 + idx];
        }
        __syncthreads();
        #pragma unroll 4
        for (int c2 = 0; c2 < 64; ++c2) {
            const f32x4 wv = *(const f32x4*)&Wl[c2 * 64 + fg * 4];
            #pragma unroll
            for (int m = 0; m < 4; ++m) {
                const float hv = ht[(ns * 4 + m) * 129 + half * 64 + c2];
                acc[m] += wv * hv;
            }
        }
    }

    const f32x4 a1v = *(const f32x4*)&a[fg * 4];
    const f32x4 a2v = *(const f32x4*)&a[NF + fg * 4];
    #pragma unroll
    for (int m = 0; m < 4; ++m) {
        float p1 = acc[m].x * a1v.x + acc[m].y * a1v.y + acc[m].z * a1v.z + acc[m].w * a1v.w;
        float p2 = acc[m].x * a2v.x + acc[m].y * a2v.y + acc[m].z * a2v.z + acc[m].w * a2v.w;
        #pragma unroll
        for (int d = 1; d < 16; d <<= 1) {
            p1 += __shfl_xor(p1, d, 64);
            p2 += __shfl_xor(p2, d, 64);
        }
        if (fg == 0) {
            const int n = n0 + ns * 4 + m;
            s1g[(size_t)b * NN + n] = p1;
            s2g[(size_t)b * NN + n] = p2;
        }
    }
    #pragma unroll
    for (int q = 0; q < 4; ++q) {
        f16x4 v;
        v[0] = (_Float16)acc[0][q]; v[1] = (_Float16)acc[1][q];
        v[2] = (_Float16)acc[2][q]; v[3] = (_Float16)acc[3][q];
        const int f = fg * 4 + q;
        *(f16x4*)&wht[((size_t)b * NF + f) * NN + n0 + ns * 4] = v;
    }
}

// Kernel 2: fused wave-autonomous flash-GAT, separable-exp P-gen.
//   p_ij = exp2(K*(lrelu(s1_i+s2_j) - M_i)) = max(A1_i*E1_j, A2_i*E2_j)
// with per-col tables E1/E2 in LDS (built once) and per-row A1/A2 in VGPRs.
// Hot loop: NO transcendentals, NO lrelu — 2 mul + max + cmp + sel per elem.
// Block = 8 waves (512 thr): 2 row-groups x 4 j-quarters; wave = 16 rows x
// 512 cols = 8 chunks of 64. Partials additive (fixed shift), combined once.
// launch_bounds(512,4): VGPR cap 128, audited budget ~110 -> 4 waves/SIMD.
//
// GRID CONTRACT (R4/R7 bug class): decode is p = (hi<<9)|(strip<<3)|xcd with
// hi in [0,2), strip in [0,64), xcd in [0,8)  ==> grid MUST be 2*64*8 = 1024.
#define K2_N_HI    2
#define K2_N_STRIP 64
#define K2_N_XCD   8
__global__ __launch_bounds__(512, 4) void k_attn(
    const float* __restrict__ g, const _Float16* __restrict__ wht,
    const float* __restrict__ s1g, const float* __restrict__ s2g,
    float* __restrict__ out)
{
    __shared__ float ET[2 * NN];                     // 16 KB: interleaved (E1,E2) per col
    __shared__ float s1b[32];
    __shared__ float wred[8];
    __shared__ __align__(16) _Float16 Pc[8][1024];   // 16 KB: per-wave 16 rows x 64 f16
    __shared__ f32x4 accS[2][3][5][64];              // 30 KB: jq>=1 partials

    const int t = threadIdx.x;
    const int lane = t & 63;
    const int w = t >> 6;                            // wave 0..7
    const int rg = w & 1, jq = w >> 1;               // row-group, j-quarter

    const int p = blockIdx.x;
    const int b = (p & 7) + ((p >> 9) << 3);
    const int strip = (p >> 3) & 63;
    const int i0 = strip * 32 + rg * 16;             // wave's first row

    // ---- prologue: E1/E2 tables (each thread: 4 cols), s1 tile, block max(s2) ----
    const f32x4 s2v = *(const f32x4*)&s2g[(size_t)b * NN + t * 4];
    {
        f32x4 ia, ib;
        ia.x = __builtin_amdgcn_exp2f(EXP_K * s2v.x);
        ia.y = __builtin_amdgcn_exp2f(EXP_K * NEG_SLOPE * s2v.x);
        ia.z = __builtin_amdgcn_exp2f(EXP_K * s2v.y);
        ia.w = __builtin_amdgcn_exp2f(EXP_K * NEG_SLOPE * s2v.y);
        ib.x = __builtin_amdgcn_exp2f(EXP_K * s2v.z);
        ib.y = __builtin_amdgcn_exp2f(EXP_K * NEG_SLOPE * s2v.z);
        ib.z = __builtin_amdgcn_exp2f(EXP_K * s2v.w);
        ib.w = __builtin_amdgcn_exp2f(EXP_K * NEG_SLOPE * s2v.w);
        *(f32x4*)&ET[t * 8]     = ia;
        *(f32x4*)&ET[t * 8 + 4] = ib;
    }
    if (t < 32) s1b[t] = s1g[(size_t)b * NN + strip * 32 + t];
    float lm = fmaxf(fmaxf(s2v.x, s2v.y), fmaxf(s2v.z, s2v.w));
    #pragma unroll
    for (int d = 1; d < 64; d <<= 1) lm = fmaxf(lm, __shfl_xor(lm, d, 64));
    if (lane == 0) wred[w] = lm;
    __syncthreads();
    float S2MAX = wred[0];
    #pragma unroll
    for (int q = 1; q < 8; ++q) S2MAX = fmaxf(S2MAX, wred[q]);

    // per-lane row constants: A1 = 2^(K(s1-M)), A2 = 2^(K(0.33*s1-M)), M = lrelu(s1+S2MAX)
    const int rh = lane >> 5;                        // row parity
    const int cp = lane & 31;                        // col-pair index
    float A1[8], A2[8];
    #pragma unroll
    for (int u = 0; u < 8; ++u) {
        const float v = s1b[rg * 16 + u * 2 + rh];
        const float M = lrelu(v + S2MAX);
        A1[u] = __builtin_amdgcn_exp2f(EXP_K * (v - M));
        A2[u] = __builtin_amdgcn_exp2f(EXP_K * (NEG_SLOPE * v - M));
    }

    const float* gp = g + (size_t)b * NN * NN + (size_t)i0 * NN + jq * 512 + cp * 2;
    const int fc = lane & 15, kg = lane >> 4;
    const _Float16* wb = wht + ((size_t)b * NF + fc) * NN + jq * 512 + kg * 8;
    char* pcb = (char*)&Pc[w][0];

    f32x4 acc0 = {0,0,0,0}, acc1 = {0,0,0,0}, acc2 = {0,0,0,0}, acc3 = {0,0,0,0};
    f32x4 acc_s = {0,0,0,0};                         // exact row sums via ones-MFMA
    f16x8 ones;
    #pragma unroll
    for (int u = 0; u < 8; ++u) ones[u] = (_Float16)1.0f;

    // ring-2 g buffers; refill with ch+2 after P-gen consumes (WAR-ordered by compiler)
    f32x2 gA[8], gB[8];
    #pragma unroll
    for (int u = 0; u < 8; ++u) gA[u] = *(const f32x2*)(gp + (size_t)(u * 2 + rh) * NN);
    #pragma unroll
    for (int u = 0; u < 8; ++u) gB[u] = *(const f32x2*)(gp + (size_t)(u * 2 + rh) * NN + 64);

#define CHUNK_BODY(CH, CUR)                                                    \
    {                                                                          \
        const int ch_ = (CH);                                                  \
        /* ks=0 B-frags (staged: ks=1 loaded after first MFMA set, halves regs) */ \
        f16x8 bfa[4];                                                          \
        _Pragma("unroll")                                                      \
        for (int ft = 0; ft < 4; ++ft)                                         \
            bfa[ft] = *(const f16x8*)(wb + (size_t)ft * 16 * NN + ch_ * 64);   \
        /* P-gen: p = mask ? max(A1*E1, A2*E2) : 0 */                          \
        const f32x4 ev = *(const f32x4*)&ET[jq * 1024 + ch_ * 128 + cp * 4];   \
        _Pragma("unroll")                                                      \
        for (int u = 0; u < 8; ++u) {                                          \
            const int row = u * 2 + rh;                                        \
            const float m0 = fmaxf(A1[u] * ev.x, A2[u] * ev.y);                \
            const float m1 = fmaxf(A1[u] * ev.z, A2[u] * ev.w);                \
            const float p0 = (CUR[u].x > 0.0f) ? m0 : 0.0f;                    \
            const float p1 = (CUR[u].y > 0.0f) ? m1 : 0.0f;                    \
            f16x2 pv; pv[0] = (_Float16)p0; pv[1] = (_Float16)p1;              \
            *(f16x2*)(pcb + ((row * 128 + cp * 4) ^ ((row & 7) << 4))) = pv;   \
        }                                                                      \
        /* refill CUR with chunk ch+2 (after last CUR read) */                 \
        if (ch_ < 6) {                                                         \
            _Pragma("unroll")                                                  \
            for (int u = 0; u < 8; ++u)                                        \
                CUR[u] = *(const f32x2*)(gp + (size_t)(u * 2 + rh) * NN        \
                                         + (ch_ + 2) * 64);                    \
        }                                                                      \
        /* A-frags + MFMA: ks=0 set, then ks=1 B-frags + second set */         \
        const f16x8 af0 = *(const f16x8*)(pcb +                                \
            ((fc * 128 + kg * 16) ^ ((fc & 7) << 4)));                         \
        const f16x8 af1 = *(const f16x8*)(pcb +                                \
            ((fc * 128 + 64 + kg * 16) ^ ((fc & 7) << 4)));                    \
        acc0  = __builtin_amdgcn_mfma_f32_16x16x32_f16(af0, bfa[0], acc0, 0, 0, 0); \
        acc1  = __builtin_amdgcn_mfma_f32_16x16x32_f16(af0, bfa[1], acc1, 0, 0, 0); \
        acc2  = __builtin_amdgcn_mfma_f32_16x16x32_f16(af0, bfa[2], acc2, 0, 0, 0); \
        acc3  = __builtin_amdgcn_mfma_f32_16x16x32_f16(af0, bfa[3], acc3, 0, 0, 0); \
        acc_s = __builtin_amdgcn_mfma_f32_16x16x32_f16(af0, ones,   acc_s, 0, 0, 0); \
        _Pragma("unroll")                                                      \
        for (int ft = 0; ft < 4; ++ft)                                         \
            bfa[ft] = *(const f16x8*)(wb + (size_t)ft * 16 * NN + ch_ * 64 + 32); \
        acc0  = __builtin_amdgcn_mfma_f32_16x16x32_f16(af1, bfa[0], acc0, 0, 0, 0); \
        acc1  = __builtin_amdgcn_mfma_f32_16x16x32_f16(af1, bfa[1], acc1, 0, 0, 0); \
        acc2  = __builtin_amdgcn_mfma_f32_16x16x32_f16(af1, bfa[2], acc2, 0, 0, 0); \
        acc3  = __builtin_amdgcn_mfma_f32_16x16x32_f16(af1, bfa[3], acc3, 0, 0, 0); \
        acc_s = __builtin_amdgcn_mfma_f32_16x16x32_f16(af1, ones,   acc_s, 0, 0, 0); \
    }

    #pragma unroll 1
    for (int it = 0; it < 4; ++it) {
        CHUNK_BODY(it * 2,     gA);
        CHUNK_BODY(it * 2 + 1, gB);
    }
#undef CHUNK_BODY

    // ---- epilogue: combine 4 j-quarter partials (additive), normalize, store ----
    if (jq >= 1) {
        accS[rg][jq - 1][0][lane] = acc0;
        accS[rg][jq - 1][1][lane] = acc1;
        accS[rg][jq - 1][2][lane] = acc2;
        accS[rg][jq - 1][3][lane] = acc3;
        accS[rg][jq - 1][4][lane] = acc_s;
    }
    __syncthreads();
    if (jq == 0) {
        #pragma unroll
        for (int q3 = 0; q3 < 3; ++q3) {
            acc0  += accS[rg][q3][0][lane];
            acc1  += accS[rg][q3][1][lane];
            acc2  += accS[rg][q3][2][lane];
            acc3  += accS[rg][q3][3][lane];
            acc_s += accS[rg][q3][4][lane];
        }
        f32x4 rinv;
        #pragma unroll
        for (int q = 0; q < 4; ++q) rinv[q] = 1.0f / acc_s[q];

        const size_t ob = ((size_t)b * NF + fc) * NN + (size_t)i0 + kg * 4;
        f32x4 o0, o1, o2, o3;
        #pragma unroll
        for (int q = 0; q < 4; ++q) {    // D row m = kg*4+q (m89-verified), col = fc
            o0[q] = acc0[q] * rinv[q];
            o1[q] = acc1[q] * rinv[q];
            o2[q] = acc2[q] * rinv[q];
            o3[q] = acc3[q] * rinv[q];
        }
        *(f32x4*)&out[ob]                   = o0;
        *(f32x4*)&out[ob + (size_t)16 * NN] = o1;
        *(f32x4*)&out[ob + (size_t)32 * NN] = o2;
        *(f32x4*)&out[ob + (size_t)48 * NN] = o3;
    }
}

extern "C" void kernel_launch(void* const* d_in, const int* in_sizes, int n_in,
                              void* d_out, int out_size, void* d_ws, size_t ws_size,
                              hipStream_t stream)
{
    (void)in_sizes; (void)n_in; (void)out_size; (void)ws_size;
    const float* h = (const float*)d_in[0];
    const float* g = (const float*)d_in[1];
    const float* W = (const float*)d_in[2];
    const float* a = (const float*)d_in[3];
    float* out = (float*)d_out;

    // workspace: WhT f16 (4 MiB) | s1 (128 KiB) | s2 (128 KiB)
    char* ws = (char*)d_ws;
    _Float16* wht = (_Float16*)ws;
    float* s1 = (float*)(ws + (size_t)NB * NF * NN * sizeof(_Float16));
    float* s2 = s1 + (size_t)NB * NN;

    k_precompute<<<NB * (NN / 64), 256, 0, stream>>>(h, W, a, wht, s1, s2);
    // grid derived from the decode's factor sizes — R4/R7 bug class guard
    k_attn<<<K2_N_HI * K2_N_STRIP * K2_N_XCD, 512, 0, stream>>>(g, wht, s1, s2, out);
}

// Round 12
// 97.801 us; speedup vs baseline: 1.3865x; 1.3865x over previous
//
#include <hip/hip_runtime.h>
#include <hip/hip_bf16.h>

#define NB 16
#define NC 128
#define NN 2048
#define NF 64
#define NEG_SLOPE 0.33f
#define EXP_K 1.4426950408889634f   // log2(e): pre-scale so exp() is exp2()

typedef float    f32x2 __attribute__((ext_vector_type(2)));
typedef float    f32x4 __attribute__((ext_vector_type(4)));
typedef _Float16 f16x2 __attribute__((ext_vector_type(2)));
typedef _Float16 f16x4 __attribute__((ext_vector_type(4)));
typedef _Float16 f16x8 __attribute__((ext_vector_type(8)));

__device__ __forceinline__ float lrelu(float x) {
    return fmaxf(x, x * NEG_SLOPE);   // valid leaky-relu for slope<1; commutes with positive scaling
}

// Kernel 1: Wh = h^T @ W in fp32 (VALU, LDS-tiled); emit WhT f16 [b][f][n],
// s1 = Wh@a1, s2 = Wh@a2 in fp32.  (unchanged)
__global__ __launch_bounds__(256) void k_precompute(
    const float* __restrict__ h, const float* __restrict__ W,
    const float* __restrict__ a, _Float16* __restrict__ wht,
    float* __restrict__ s1g, float* __restrict__ s2g)
{
    __shared__ float Wl[64 * 64];
    __shared__ float ht[64 * 129];

    const int t = threadIdx.x;
    const int b = blockIdx.x >> 5;
    const int n0 = (blockIdx.x & 31) << 6;
    const int lane = t & 63, cg = t >> 6;

    #pragma unroll 8
    for (int k = 0; k < 32; ++k) {
        const int c = cg * 32 + k;
        ht[lane * 129 + c] = h[(size_t)(b * NC + c) * NN + n0 + lane];
    }

    const int fg = t & 15, ns = t >> 4;
    f32x4 acc[4] = {};
    for (int half = 0; half < 2; ++half) {
        if (half) __syncthreads();
        #pragma unroll
        for (int k = 0; k < 4; ++k) {
            const int idx = k * 1024 + t * 4;
            *(f32x4*)&Wl[idx] = *(const f32x4*)&W[half * 4096 + idx];
        }
        __syncthreads();
        #pragma unroll 4
        for (int c2 = 0; c2 < 64; ++c2) {
            const f32x4 wv = *(const f32x4*)&Wl[c2 * 64 + fg * 4];
            #pragma unroll
            for (int m = 0; m < 4; ++m) {
                const float hv = ht[(ns * 4 + m) * 129 + half * 64 + c2];
                acc[m] += wv * hv;
            }
        }
    }

    const f32x4 a1v = *(const f32x4*)&a[fg * 4];
    const f32x4 a2v = *(const f32x4*)&a[NF + fg * 4];
    #pragma unroll
    for (int m = 0; m < 4; ++m) {
        float p1 = acc[m].x * a1v.x + acc[m].y * a1v.y + acc[m].z * a1v.z + acc[m].w * a1v.w;
        float p2 = acc[m].x * a2v.x + acc[m].y * a2v.y + acc[m].z * a2v.z + acc[m].w * a2v.w;
        #pragma unroll
        for (int d = 1; d < 16; d <<= 1) {
            p1 += __shfl_xor(p1, d, 64);
            p2 += __shfl_xor(p2, d, 64);
        }
        if (fg == 0) {
            const int n = n0 + ns * 4 + m;
            s1g[(size_t)b * NN + n] = p1;
            s2g[(size_t)b * NN + n] = p2;
        }
    }
    #pragma unroll
    for (int q = 0; q < 4; ++q) {
        f16x4 v;
        v[0] = (_Float16)acc[0][q]; v[1] = (_Float16)acc[1][q];
        v[2] = (_Float16)acc[2][q]; v[3] = (_Float16)acc[3][q];
        const int f = fg * 4 + q;
        *(f16x4*)&wht[((size_t)b * NF + f) * NN + n0 + ns * 4] = v;
    }
}

// Kernel 2: wave-autonomous flash-GAT, j-split, ring-3 depth-2 g prefetch.
// IDENTICAL to the R8 kernel except __launch_bounds__(256) with NO waves-per-EU
// hint: every build with a 2nd arg >= 2 came back VGPR in {40,64} and spilled
// the ~110-VGPR chunk-loop state to scratch (R10 counters: VGPR=64, VALUBusy
// 11%, MfmaUtil 2.7%, HBM 18% -- pure scratch-latency bound). Working set must
// stay register-resident; occupancy beyond 4 waves/SIMD is NOT needed.
//
// GRID CONTRACT (R4/R7 bug class): decode is p = (hi<<9)|(strip<<3)|xcd with
// hi in [0,2), strip in [0,64), xcd in [0,8)  ==> grid MUST be 2*64*8 = 1024.
#define K2_N_HI    2
#define K2_N_STRIP 64
#define K2_N_XCD   8
__global__ __launch_bounds__(256) void k_attn(
    const float* __restrict__ g, const _Float16* __restrict__ wht,
    const float* __restrict__ s1g, const float* __restrict__ s2g,
    float* __restrict__ out)
{
    __shared__ float s2b[NN];                        // 8 KB (pre-scaled by log2 e)
    __shared__ float s1b[32];
    __shared__ float wred[4];
    __shared__ __align__(16) _Float16 Pc[4][1024];   // per-wave 16 rows x 64 f16 (2 KB each)
    __shared__ f32x4 accS[2][5][64];                 // jq=1 partials: [rg][acc0..3,sums][lane]

    const int t = threadIdx.x;
    const int lane = t & 63;
    const int w = t >> 6;                            // wave 0..3
    const int rg = w & 1, jq = w >> 1;               // row-group, j-half

    // XCD-pinned decode: p = (hi<<9)|(strip<<3)|xcd -> b = xcd + 8*hi (bijective, 1024 blocks)
    const int p = blockIdx.x;
    const int b = (p & 7) + ((p >> 9) << 3);
    const int strip = (p >> 3) & 63;
    const int i0 = strip * 32 + rg * 16;             // wave's first row

    // ---- prologue: scaled s2 -> LDS, s1 tile, block max(s2) (the ONLY pre-epilogue barrier) ----
    f32x4 sA = *(const f32x4*)&s2g[(size_t)b * NN + t * 8];
    f32x4 sB = *(const f32x4*)&s2g[(size_t)b * NN + t * 8 + 4];
    sA *= EXP_K; sB *= EXP_K;
    *(f32x4*)&s2b[t * 8] = sA;
    *(f32x4*)&s2b[t * 8 + 4] = sB;
    if (t < 32) s1b[t] = s1g[(size_t)b * NN + strip * 32 + t] * EXP_K;
    float lm = fmaxf(fmaxf(fmaxf(sA.x, sA.y), fmaxf(sA.z, sA.w)),
                     fmaxf(fmaxf(sB.x, sB.y), fmaxf(sB.z, sB.w)));
    #pragma unroll
    for (int d = 1; d < 64; d <<= 1) lm = fmaxf(lm, __shfl_xor(lm, d, 64));
    if (lane == 0) wred[w] = lm;
    __syncthreads();
    const float S2MAX = fmaxf(fmaxf(wred[0], wred[1]), fmaxf(wred[2], wred[3]));

    // per-lane row constants (VGPRs, statically indexed by u — rule #20)
    const int rh = lane >> 5;                        // row parity handled by this lane
    const int cp = lane & 31;                        // col-pair index
    float s1u[8], Mu[8];
    #pragma unroll
    for (int u = 0; u < 8; ++u) {
        const float v = s1b[rg * 16 + u * 2 + rh];
        s1u[u] = v;
        Mu[u]  = lrelu(v + S2MAX);                   // scaled upper bound on row scores
    }

    const float* gp = g + (size_t)b * NN * NN + (size_t)i0 * NN + jq * 1024 + cp * 2;
    const int fc = lane & 15, kg = lane >> 4;
    const _Float16* wb = wht + ((size_t)b * NF + fc) * NN + jq * 1024 + kg * 8;
    char* pcb = (char*)&Pc[w][0];

    f32x4 acc0 = {0,0,0,0}, acc1 = {0,0,0,0}, acc2 = {0,0,0,0}, acc3 = {0,0,0,0};
    f32x4 acc_s = {0,0,0,0};                         // row sums via ones-MFMA (R5-verified)
    f16x8 ones;
    #pragma unroll
    for (int u = 0; u < 8; ++u) ones[u] = (_Float16)1.0f;

    // ring-3 g buffers: buf(c) = c mod 3; depth-2 prefetch (chunk c issues c+2)
    f32x2 gA[8], gB[8], gC[8];
    #pragma unroll
    for (int u = 0; u < 8; ++u) gA[u] = *(const f32x2*)(gp + (size_t)(u * 2 + rh) * NN);
    #pragma unroll
    for (int u = 0; u < 8; ++u) gB[u] = *(const f32x2*)(gp + (size_t)(u * 2 + rh) * NN + 64);

#define CHUNK_BODY(CH, CUR, PF)                                                \
    {                                                                          \
        const int ch_ = (CH);                                                  \
        /* [1] wht B-frags for THIS chunk (issued first: MFMA wait won't drain g) */ \
        f16x8 bfv[2][4];                                                       \
        _Pragma("unroll")                                                      \
        for (int ks = 0; ks < 2; ++ks) {                                       \
            _Pragma("unroll")                                                  \
            for (int ft = 0; ft < 4; ++ft)                                     \
                bfv[ks][ft] = *(const f16x8*)(wb + (size_t)ft * 16 * NN        \
                                              + ch_ * 64 + ks * 32);           \
        }                                                                      \
        __builtin_amdgcn_sched_barrier(0);                                     \
        /* [2] depth-2 g prefetch (ch+2) into ring buffer PF (no WAR block) */ \
        if (ch_ < 14) {                                                        \
            _Pragma("unroll")                                                  \
            for (int u = 0; u < 8; ++u)                                        \
                PF[u] = *(const f32x2*)(gp + (size_t)(u * 2 + rh) * NN         \
                                        + (ch_ + 2) * 64);                     \
        }                                                                      \
        /* [3] P-gen: g regs -> exp2 -> wave-private swizzled LDS */           \
        const f32x2 sv = *(const f32x2*)&s2b[jq * 1024 + ch_ * 64 + cp * 2];   \
        _Pragma("unroll")                                                      \
        for (int u = 0; u < 8; ++u) {                                          \
            const int row = u * 2 + rh;                                        \
            const float p0 = (CUR[u].x > 0.0f)                                 \
                ? __builtin_amdgcn_exp2f(lrelu(s1u[u] + sv.x) - Mu[u]) : 0.0f; \
            const float p1 = (CUR[u].y > 0.0f)                                 \
                ? __builtin_amdgcn_exp2f(lrelu(s1u[u] + sv.y) - Mu[u]) : 0.0f; \
            f16x2 pv; pv[0] = (_Float16)p0; pv[1] = (_Float16)p1;              \
            *(f16x2*)(pcb + ((row * 128 + cp * 4) ^ ((row & 7) << 4))) = pv;   \
        }                                                                      \
        /* [4] A-frags + MFMA (incl. ones-MFMA exact row sums) */              \
        _Pragma("unroll")                                                      \
        for (int ks = 0; ks < 2; ++ks) {                                       \
            const f16x8 af = *(const f16x8*)(pcb +                             \
                ((fc * 128 + ks * 64 + kg * 16) ^ ((fc & 7) << 4)));           \
            acc0  = __builtin_amdgcn_mfma_f32_16x16x32_f16(af, bfv[ks][0], acc0, 0, 0, 0); \
            acc1  = __builtin_amdgcn_mfma_f32_16x16x32_f16(af, bfv[ks][1], acc1, 0, 0, 0); \
            acc2  = __builtin_amdgcn_mfma_f32_16x16x32_f16(af, bfv[ks][2], acc2, 0, 0, 0); \
            acc3  = __builtin_amdgcn_mfma_f32_16x16x32_f16(af, bfv[ks][3], acc3, 0, 0, 0); \
            acc_s = __builtin_amdgcn_mfma_f32_16x16x32_f16(af, ones,       acc_s, 0, 0, 0); \
        }                                                                      \
    }

    // 16 chunks, period-3 ring: c mod 3 -> {A,B,C}; prefetch target = buf((c+2)%3)
    #pragma unroll 1
    for (int c = 0; c < 15; c += 3) {
        CHUNK_BODY(c,     gA, gC);
        CHUNK_BODY(c + 1, gB, gA);
        CHUNK_BODY(c + 2, gC, gB);
    }
    CHUNK_BODY(15, gA, gC);   // 15 % 3 == 0 -> A (loaded by prefetch at c=13); no prefetch (guard)
#undef CHUNK_BODY

    // ---- epilogue: combine j-half partials (additive under fixed shift), normalize, store ----
    if (jq == 1) {
        accS[rg][0][lane] = acc0;
        accS[rg][1][lane] = acc1;
        accS[rg][2][lane] = acc2;
        accS[rg][3][lane] = acc3;
        accS[rg][4][lane] = acc_s;
    }
    __syncthreads();
    if (jq == 0) {
        acc0  += accS[rg][0][lane];
        acc1  += accS[rg][1][lane];
        acc2  += accS[rg][2][lane];
        acc3  += accS[rg][3][lane];
        acc_s += accS[rg][4][lane];
        f32x4 rinv;
        #pragma unroll
        for (int q = 0; q < 4; ++q) rinv[q] = 1.0f / acc_s[q];

        const size_t ob = ((size_t)b * NF + fc) * NN + (size_t)i0 + kg * 4;
        f32x4 o0, o1, o2, o3;
        #pragma unroll
        for (int q = 0; q < 4; ++q) {    // D row m = kg*4+q (m89-verified), col = fc
            o0[q] = acc0[q] * rinv[q];
            o1[q] = acc1[q] * rinv[q];
            o2[q] = acc2[q] * rinv[q];
            o3[q] = acc3[q] * rinv[q];
        }
        *(f32x4*)&out[ob]                   = o0;
        *(f32x4*)&out[ob + (size_t)16 * NN] = o1;
        *(f32x4*)&out[ob + (size_t)32 * NN] = o2;
        *(f32x4*)&out[ob + (size_t)48 * NN] = o3;
    }
}

extern "C" void kernel_launch(void* const* d_in, const int* in_sizes, int n_in,
                              void* d_out, int out_size, void* d_ws, size_t ws_size,
                              hipStream_t stream)
{
    (void)in_sizes; (void)n_in; (void)out_size; (void)ws_size;
    const float* h = (const float*)d_in[0];
    const float* g = (const float*)d_in[1];
    const float* W = (const float*)d_in[2];
    const float* a = (const float*)d_in[3];
    float* out = (float*)d_out;

    // workspace: WhT f16 (4 MiB) | s1 (128 KiB) | s2 (128 KiB)
    char* ws = (char*)d_ws;
    _Float16* wht = (_Float16*)ws;
    float* s1 = (float*)(ws + (size_t)NB * NF * NN * sizeof(_Float16));
    float* s2 = s1 + (size_t)NB * NN;

    k_precompute<<<NB * (NN / 64), 256, 0, stream>>>(h, W, a, wht, s1, s2);
    // grid derived from the decode's factor sizes — R4/R7 bug class guard
    k_attn<<<K2_N_HI * K2_N_STRIP * K2_N_XCD, 256, 0, stream>>>(g, wht, s1, s2, out);
}